// Round 14
// baseline (535.790 us; speedup 1.0000x reference)
//
#include <hip/hip_runtime.h>
#include <hip/hip_bf16.h>

// VectorQuantizer B=32768, K=4096, D=512, fp32 in/out.
// Out concat (f32): quantized_st[B*512] | indices[B] | loss | perplexity | encodings[B*4096].
// R14: barrier-free K-loop screen. Tile 128x64; FULL B (64 cols x 512 K, 64KB bf16)
// staged to LDS once (1 barrier total); K-loop streams A-frags from L2-resident Xbf
// with no forced drains. rb-major-per-XCD swizzle keeps X window + Ebf3 L2-hot.
// shfl_xor top-2 epilogue (R12-validated); partials/reduce/encq/fin/npsum verbatim.

typedef __attribute__((ext_vector_type(8))) short bf16x8;
typedef __attribute__((ext_vector_type(4))) float f32x4;

#define BB 32768
#define KK 4096
#define DD 512

#define IDX_OFF  (BB*DD)
#define LOSS_OFF (IDX_OFF + BB)
#define PERP_OFF (LOSS_OFF + 1)
#define ENC_OFF  (PERP_OFF + 1)

// ws byte offsets
#define WSB_XSQ  0
#define WSB_ESQ  131072
#define WSB_IDX  147456
#define WSB_HIST 278528
#define WSB_LOSS 294912
#define WSB_EBF3 294928          // 4 MB: E bf16, packed per-cbb 64KB chunk
#define WSB_XBF  4489232         // 32 MB: X bf16, fragment-packed (R13 layout)
#define WSB_PART 38043664        // 16 MB: uint2 partials [64][32768]

#define MARG 2.5e-4f
#define NCAND 16

static __device__ __forceinline__ unsigned short f2bf(float f) {
    __hip_bfloat16 h = __float2bfloat16(f);
    return *reinterpret_cast<unsigned short*>(&h);
}

static __device__ __forceinline__ unsigned int packscore(float s, int col) {
    unsigned int u = __float_as_uint(s);
    u ^= (u & 0x80000000u) ? 0xFFFFFFFFu : 0x80000000u;
    return (u & 0xFFFFF000u) | (unsigned int)col;
}
static __device__ __forceinline__ float unpackscore(unsigned int p) {
    unsigned int u = p & 0xFFFFF000u;
    u = (u & 0x80000000u) ? (u ^ 0x80000000u) : ~u;
    return __uint_as_float(u);
}

static __device__ __forceinline__ void gll16(const void* g, void* l) {
    __builtin_amdgcn_global_load_lds(
        (const __attribute__((address_space(1))) unsigned int*)g,
        (__attribute__((address_space(3))) unsigned int*)l, 16, 0, 0);
}

// numpy-emulated row sum-of-squares (tree bit-identical R5-R13) fused with X packing.
__global__ __launch_bounds__(256) void npsum_pack_kernel(const float* __restrict__ X,
                                                         const float* __restrict__ E,
                                                         float* __restrict__ xsq,
                                                         float* __restrict__ esq,
                                                         unsigned short* __restrict__ Xbf) {
    __shared__ float sq[4][512];
    __shared__ float ub[4][64];
    __shared__ float bb[4][4];
    int w = threadIdx.x >> 6, lane = threadIdx.x & 63;
    int row = blockIdx.x * 4 + w;
    const float* src; float* dst;
    bool isx = (row < BB);
    if (isx) { src = X + (size_t)row * DD;        dst = xsq + row; }
    else     { src = E + (size_t)(row - BB) * DD; dst = esq + (row - BB); }
    const float4* s4 = (const float4*)(src + lane * 8);
    float4 a = s4[0], b = s4[1];
    sq[w][lane * 8 + 0] = __fmul_rn(a.x, a.x);
    sq[w][lane * 8 + 1] = __fmul_rn(a.y, a.y);
    sq[w][lane * 8 + 2] = __fmul_rn(a.z, a.z);
    sq[w][lane * 8 + 3] = __fmul_rn(a.w, a.w);
    sq[w][lane * 8 + 4] = __fmul_rn(b.x, b.x);
    sq[w][lane * 8 + 5] = __fmul_rn(b.y, b.y);
    sq[w][lane * 8 + 6] = __fmul_rn(b.z, b.z);
    sq[w][lane * 8 + 7] = __fmul_rn(b.w, b.w);
    if (isx) {   // Xbf unit for [row][lane*8 ..+7] (R13 layout)
        int kt64 = lane >> 3, ks = (lane >> 2) & 1, oct = lane & 3;
        int rf = (row >> 4) & 15;
        size_t unit = ((size_t)((row >> 8) * 8 + kt64)) * 2048
                    + (size_t)((rf * 2 + ks) * 64 + oct * 16 + (row & 15));
        union { bf16x8 v; unsigned short us[8]; } pk;
        pk.us[0] = f2bf(a.x); pk.us[1] = f2bf(a.y); pk.us[2] = f2bf(a.z); pk.us[3] = f2bf(a.w);
        pk.us[4] = f2bf(b.x); pk.us[5] = f2bf(b.y); pk.us[6] = f2bf(b.z); pk.us[7] = f2bf(b.w);
        *(bf16x8*)(Xbf + unit * 8) = pk.v;
    }
    __syncthreads();
    {
        int b2 = lane >> 4, l = lane & 15;
        const float* s = &sq[w][b2 * 128];
        float t = __fadd_rn(
            __fadd_rn(__fadd_rn(s[l], s[16 + l]), __fadd_rn(s[32 + l], s[48 + l])),
            __fadd_rn(__fadd_rn(s[64 + l], s[80 + l]), __fadd_rn(s[96 + l], s[112 + l])));
        ub[w][lane] = t;
    }
    __syncthreads();
    if (lane < 4) {
        const float* u = &ub[w][lane * 16];
        float T3[8], T6[4];
        #pragma unroll
        for (int i = 0; i < 8; ++i) T3[i] = __fadd_rn(u[i], u[i + 8]);
        #pragma unroll
        for (int i = 0; i < 4; ++i) T6[i] = __fadd_rn(T3[i], T3[i + 4]);
        bb[w][lane] = __fadd_rn(__fadd_rn(T6[0], T6[2]), __fadd_rn(T6[1], T6[3]));
    }
    __syncthreads();
    if (lane == 0)
        *dst = __fadd_rn(__fadd_rn(bb[w][0], bb[w][1]), __fadd_rn(bb[w][2], bb[w][3]));
}

// E fp32 -> bf16 per-cbb 64KB chunk, unit u=(ks*4+nf)*64+lane:
// holds E[cbb*64 + nf*16 + (lane&15)][ks*32 + (lane>>4)*8 ..+7].
// Also zero-inits hist/loss (fused init).
__global__ __launch_bounds__(256) void packE3_kernel(const float* __restrict__ E,
                                                     unsigned short* __restrict__ Ebf3,
                                                     int* __restrict__ hist,
                                                     double* __restrict__ loss_acc) {
    int t = blockIdx.x * 256 + threadIdx.x;
    if (t < KK) hist[t] = 0;
    if (t == KK) *loss_acc = 0.0;
    int cbb = t >> 12, u = t & 4095;
    int ks = u >> 8, nf = (u >> 6) & 3, lane = u & 63;
    int col = cbb * 64 + nf * 16 + (lane & 15);
    int k   = ks * 32 + (lane >> 4) * 8;
    const float4* s = (const float4*)(E + (size_t)col * DD + k);
    float4 a = s[0], b = s[1];
    union { bf16x8 v; unsigned short us[8]; } pk;
    pk.us[0] = f2bf(a.x); pk.us[1] = f2bf(a.y); pk.us[2] = f2bf(a.z); pk.us[3] = f2bf(a.w);
    pk.us[4] = f2bf(b.x); pk.us[5] = f2bf(b.y); pk.us[6] = f2bf(b.z); pk.us[7] = f2bf(b.w);
    *(bf16x8*)(Ebf3 + (size_t)t * 8) = pk.v;
}

// Screen: grid 16384 = 256 rb x 64 cbb (rb-major within XCD), 256 thr (4 waves).
// B full-K in LDS (64KB, staged once); barrier-free unrolled K-loop.
__global__ __launch_bounds__(256, 2) void gemm_screen(
    const unsigned short* __restrict__ Xbf, const unsigned short* __restrict__ Ebf3,
    const float* __restrict__ esqw, uint2* __restrict__ partials)
{
    __shared__ __align__(16) char Bsh[65536];

    const int tid = threadIdx.x;
    const int w = tid >> 6, lane = tid & 63;
    const int c = lane & 15, g = lane >> 4;
    const int bid = blockIdx.x;
    const int orig = (bid & 7) * 2048 + (bid >> 3);   // bijective: 16384 % 8 == 0
    const int rb = orig >> 6, cbb = orig & 63;        // rb-major per XCD
    const int row0 = rb * 128, col0 = cbb * 64;

    // stage full B chunk: 4096 units x 16B, linear (unit index == LDS offset/16)
    {
        const char* src = (const char*)Ebf3 + (size_t)cbb * 65536 + (size_t)tid * 16;
        char* dst = Bsh + w * 1024;   // +lane*16 applied by hardware
        #pragma unroll
        for (int j = 0; j < 16; ++j)
            gll16(src + j * 4096, dst + j * 4096);
    }

    const char* Xc = (const char*)Xbf + (size_t)(rb >> 1) * 262144;
    const int rfb = (rb & 1) * 8 + w * 2;             // row-frag base within 256-chunk

    f32x4 acc[2][4];
    #pragma unroll
    for (int i = 0; i < 2; ++i)
        #pragma unroll
        for (int j = 0; j < 4; ++j) acc[i][j] = (f32x4){0.f, 0.f, 0.f, 0.f};

    __syncthreads();   // B resident (drains staging)

    // barrier-free K-loop: 16 ks x {2 A global loads, 4 B LDS reads, 8 MFMA}
    #pragma unroll
    for (int ks = 0; ks < 16; ++ks) {
        const size_t base = (size_t)(ks >> 1) * 32768 + (size_t)(ks & 1) * 1024
                          + (size_t)lane * 16;
        bf16x8 a0 = *(const bf16x8*)(Xc + base + (size_t)(rfb + 0) * 2048);
        bf16x8 a1 = *(const bf16x8*)(Xc + base + (size_t)(rfb + 1) * 2048);
        #pragma unroll
        for (int nf = 0; nf < 4; ++nf) {
            bf16x8 b = *(const bf16x8*)(Bsh + (((ks * 4 + nf) * 64) + lane) * 16);
            acc[0][nf] = __builtin_amdgcn_mfma_f32_16x16x32_bf16(a0, b, acc[0][nf], 0, 0, 0);
            acc[1][nf] = __builtin_amdgcn_mfma_f32_16x16x32_bf16(a1, b, acc[1][nf], 0, 0, 0);
        }
    }

    // epilogue: per-(mf,r) top2 over 4 nf, shfl_xor merge across 16 c-lanes
    float es[4];
    #pragma unroll
    for (int nf = 0; nf < 4; ++nf) es[nf] = esqw[col0 + nf * 16 + c];
    #pragma unroll
    for (int mf = 0; mf < 2; ++mf) {
        #pragma unroll
        for (int r = 0; r < 4; ++r) {
            unsigned int q1 = 0xFFFFFFFFu, q2 = 0xFFFFFFFFu;
            #pragma unroll
            for (int nf = 0; nf < 4; ++nf) {
                int col = col0 + nf * 16 + c;
                float s = fmaf(-2.0f, acc[mf][nf][r], es[nf]);
                unsigned int q = packscore(s, col);
                if (q < q1) { q2 = q1; q1 = q; } else if (q < q2) q2 = q;
            }
            #pragma unroll
            for (int off = 1; off < 16; off <<= 1) {
                unsigned int o1 = (unsigned int)__shfl_xor((int)q1, off, 64);
                unsigned int o2 = (unsigned int)__shfl_xor((int)q2, off, 64);
                unsigned int n1 = min(q1, o1);
                unsigned int n2 = min(max(q1, o1), min(q2, o2));
                q1 = n1; q2 = n2;
            }
            if (c == 0) {
                int row = row0 + w * 32 + mf * 16 + g * 4 + r;
                partials[(size_t)cbb * BB + row] = make_uint2(q1, q2);
            }
        }
    }
}

// merge partials -> candidates -> numpy-fp32 rescore -> idx/hist/loss (verbatim R11-R13)
__global__ __launch_bounds__(256) void reduce_kernel(
    const float* __restrict__ X, const float* __restrict__ E,
    const float* __restrict__ xsqw, const float* __restrict__ esqw,
    const uint2* __restrict__ partials, int* __restrict__ idxbuf,
    int* __restrict__ hist, double* __restrict__ loss_acc,
    float* __restrict__ out)
{
    __shared__ double lred[256];
    const int row = blockIdx.x * 256 + threadIdx.x;
    unsigned int m = 0xFFFFFFFFu;
    for (int e = 0; e < 64; ++e) m = min(m, partials[(size_t)e * BB + row].x);
    float lim = unpackscore(m) + MARG;
    int cand[NCAND]; int nc = 0;
    for (int e = 0; e < 64; ++e) {
        uint2 p = partials[(size_t)e * BB + row];
        if (unpackscore(p.x) <= lim && nc < NCAND) cand[nc++] = (int)(p.x & 0xFFFu);
        if (unpackscore(p.y) <= lim && nc < NCAND) cand[nc++] = (int)(p.y & 0xFFFu);
    }
    const float* xr = X + (size_t)row * DD;
    float xs = xsqw[row];
    float bd = 3.0e38f; int bk = 0x7fffffff;
    for (int cidx = 0; cidx < nc; ++cidx) {
        int k = cand[cidx] & (KK - 1);
        const float* er = E + (size_t)k * DD;
        float q1 = 0.f, q2 = 0.f;
        for (int d = 0; d < 384; ++d)   q1 = fmaf(xr[d], er[d], q1);
        for (int d = 384; d < 512; ++d) q2 = fmaf(xr[d], er[d], q2);
        float dot = __fadd_rn(q1, q2);
        float t1  = __fadd_rn(xs, esqw[k]);
        float dnp = __fsub_rn(t1, __fmul_rn(2.0f, dot));
        if (dnp < bd || (dnp == bd && k < bk)) { bd = dnp; bk = k; }
    }
    const float* er = E + (size_t)bk * DD;
    double ls = 0.0;
    for (int d = 0; d < DD; ++d) {
        double df = (double)xr[d] - (double)er[d];
        ls = fma(df, df, ls);
    }
    idxbuf[row] = bk;
    out[IDX_OFF + row] = (float)bk;
    atomicAdd(&hist[bk], 1);
    lred[threadIdx.x] = ls;
    __syncthreads();
    for (int t = 128; t > 0; t >>= 1) {
        if (threadIdx.x < t) lred[threadIdx.x] += lred[threadIdx.x + t];
        __syncthreads();
    }
    if (threadIdx.x == 0) atomicAdd(loss_acc, lred[0]);
}

// one block per row: quantized gather (coalesced) + one-hot row
__global__ __launch_bounds__(256) void encq_kernel(const int* __restrict__ idxbuf,
                                                   const float* __restrict__ E,
                                                   float* __restrict__ out) {
    int row = blockIdx.x;
    int idx = idxbuf[row];
    ((float2*)out)[(size_t)row * 256 + threadIdx.x] =
        ((const float2*)E)[(size_t)idx * 256 + threadIdx.x];
    float2* erow = (float2*)(out + ENC_OFF) + (size_t)row * (KK / 2);
    int half = idx >> 1;
    float2 one;
    if (idx & 1) { one.x = 0.f; one.y = 1.f; } else { one.x = 1.f; one.y = 0.f; }
    float2 z; z.x = 0.f; z.y = 0.f;
    for (int c = threadIdx.x; c < KK / 2; c += 256)
        erow[c] = (c == half) ? one : z;
}

__global__ __launch_bounds__(256) void fin_kernel(const int* __restrict__ hist,
                                                  const double* __restrict__ loss_acc,
                                                  float* __restrict__ out) {
    __shared__ double red[256];
    int tid = threadIdx.x;
    double s = 0.0;
    for (int k = tid; k < KK; k += 256) {
        double p = (double)hist[k] * (1.0 / 32768.0);
        s += p * log(p + 1e-10);
    }
    red[tid] = s;
    __syncthreads();
    for (int t = 128; t > 0; t >>= 1) {
        if (tid < t) red[tid] += red[tid + t];
        __syncthreads();
    }
    if (tid == 0) {
        double perp = exp(-red[0]);
        double L = loss_acc[0] * (1.0 / ((double)BB * (double)DD));
        out[LOSS_OFF] = (float)(1.25 * L);
        out[PERP_OFF] = (float)perp;
    }
}

extern "C" void kernel_launch(void* const* d_in, const int* in_sizes, int n_in,
                              void* d_out, int out_size, void* d_ws, size_t ws_size,
                              hipStream_t stream) {
    const float* X; const float* E;
    if (in_sizes[0] == BB * DD) { X = (const float*)d_in[0]; E = (const float*)d_in[1]; }
    else                        { X = (const float*)d_in[1]; E = (const float*)d_in[0]; }
    float* out = (float*)d_out;

    float* xsq = (float*)((char*)d_ws + WSB_XSQ);
    float* esq = (float*)((char*)d_ws + WSB_ESQ);
    int* idxbuf = (int*)((char*)d_ws + WSB_IDX);
    int* hist   = (int*)((char*)d_ws + WSB_HIST);
    double* loss_acc = (double*)((char*)d_ws + WSB_LOSS);
    unsigned short* Ebf3 = (unsigned short*)((char*)d_ws + WSB_EBF3);
    unsigned short* Xbf  = (unsigned short*)((char*)d_ws + WSB_XBF);
    uint2* partials = (uint2*)((char*)d_ws + WSB_PART);

    hipLaunchKernelGGL(npsum_pack_kernel, dim3((BB + KK) / 4), dim3(256), 0, stream,
                       X, E, xsq, esq, Xbf);
    hipLaunchKernelGGL(packE3_kernel, dim3(1024), dim3(256), 0, stream,
                       E, Ebf3, hist, loss_acc);
    hipLaunchKernelGGL(gemm_screen, dim3(16384), dim3(256), 0, stream,
                       Xbf, Ebf3, esq, partials);
    hipLaunchKernelGGL(reduce_kernel, dim3(BB / 256), dim3(256), 0, stream,
                       X, E, xsq, esq, partials, idxbuf, hist, loss_acc, out);
    hipLaunchKernelGGL(encq_kernel, dim3(BB), dim3(256), 0, stream, idxbuf, E, out);
    hipLaunchKernelGGL(fin_kernel, dim3(1), dim3(256), 0, stream, hist, loss_acc, out);
}

// Round 15
// 492.715 us; speedup vs baseline: 1.0874x; 1.0874x over previous
//
#include <hip/hip_runtime.h>
#include <hip/hip_bf16.h>

// VectorQuantizer B=32768, K=4096, D=512, fp32 in/out.
// Out concat (f32): quantized_st[B*512] | indices[B] | loss | perplexity | encodings[B*4096].
// R15: 8-phase counted-vmcnt GEMM screen (T3+T4+T5 port). 256^2 tile, BK=64,
// 8 waves 2Mx4N, 128KB dyn LDS. k-slice-major pack; phase=(qk,qm) quadrant;
// 2-half-tile lookahead, vmcnt(4) at phases 3/7 (vmcnt(0) last iter p3); raw
// s_barrier; setprio around MFMA. NO __syncthreads in K-loop (no vmcnt(0) drain).
// Epilogue/partials/reduce/encq/npsum verbatim from validated R5-R13.

typedef __attribute__((ext_vector_type(8))) short bf16x8;
typedef __attribute__((ext_vector_type(4))) float f32x4;

#define BB 32768
#define KK 4096
#define DD 512

#define IDX_OFF  (BB*DD)
#define LOSS_OFF (IDX_OFF + BB)
#define PERP_OFF (LOSS_OFF + 1)
#define ENC_OFF  (PERP_OFF + 1)

// ws byte offsets
#define WSB_XSQ  0
#define WSB_ESQ  131072
#define WSB_IDX  147456
#define WSB_HIST 278528
#define WSB_LOSS 294912
#define WSB_EBF2 294928          // 4 MB: E bf16, k-slice-major 32KB chunks (cb2,kt)
#define WSB_XBF  4489232         // 32 MB: X bf16, k-slice-major 32KB chunks (rb2,kt)
#define WSB_PART 38043664        // 16 MB: uint2 partials [64][32768]

#define MARG 2.5e-4f
#define NCAND 16

static __device__ __forceinline__ unsigned short f2bf(float f) {
    __hip_bfloat16 h = __float2bfloat16(f);
    return *reinterpret_cast<unsigned short*>(&h);
}

static __device__ __forceinline__ unsigned int packscore(float s, int col) {
    unsigned int u = __float_as_uint(s);
    u ^= (u & 0x80000000u) ? 0xFFFFFFFFu : 0x80000000u;
    return (u & 0xFFFFF000u) | (unsigned int)col;
}
static __device__ __forceinline__ float unpackscore(unsigned int p) {
    unsigned int u = p & 0xFFFFF000u;
    u = (u & 0x80000000u) ? (u ^ 0x80000000u) : ~u;
    return __uint_as_float(u);
}

static __device__ __forceinline__ void gll16(const void* g, void* l) {
    __builtin_amdgcn_global_load_lds(
        (const __attribute__((address_space(1))) unsigned int*)g,
        (__attribute__((address_space(3))) unsigned int*)l, 16, 0, 0);
}

// numpy-emulated row sum-of-squares (tree bit-identical R5-R14) fused with X packing.
// k-slice-major unit: chunk*2048 + (ks*16+rf)*64 + oct*16 + (row&15).
__global__ __launch_bounds__(256) void npsum_pack_kernel(const float* __restrict__ X,
                                                         const float* __restrict__ E,
                                                         float* __restrict__ xsq,
                                                         float* __restrict__ esq,
                                                         unsigned short* __restrict__ Xbf) {
    __shared__ float sq[4][512];
    __shared__ float ub[4][64];
    __shared__ float bb[4][4];
    int w = threadIdx.x >> 6, lane = threadIdx.x & 63;
    int row = blockIdx.x * 4 + w;
    const float* src; float* dst;
    bool isx = (row < BB);
    if (isx) { src = X + (size_t)row * DD;        dst = xsq + row; }
    else     { src = E + (size_t)(row - BB) * DD; dst = esq + (row - BB); }
    const float4* s4 = (const float4*)(src + lane * 8);
    float4 a = s4[0], b = s4[1];
    sq[w][lane * 8 + 0] = __fmul_rn(a.x, a.x);
    sq[w][lane * 8 + 1] = __fmul_rn(a.y, a.y);
    sq[w][lane * 8 + 2] = __fmul_rn(a.z, a.z);
    sq[w][lane * 8 + 3] = __fmul_rn(a.w, a.w);
    sq[w][lane * 8 + 4] = __fmul_rn(b.x, b.x);
    sq[w][lane * 8 + 5] = __fmul_rn(b.y, b.y);
    sq[w][lane * 8 + 6] = __fmul_rn(b.z, b.z);
    sq[w][lane * 8 + 7] = __fmul_rn(b.w, b.w);
    if (isx) {
        int kt64 = lane >> 3, ks = (lane >> 2) & 1, oct = lane & 3;
        int rf = (row >> 4) & 15;
        size_t unit = ((size_t)((row >> 8) * 8 + kt64)) * 2048
                    + (size_t)((ks * 16 + rf) * 64 + oct * 16 + (row & 15));
        union { bf16x8 v; unsigned short us[8]; } pk;
        pk.us[0] = f2bf(a.x); pk.us[1] = f2bf(a.y); pk.us[2] = f2bf(a.z); pk.us[3] = f2bf(a.w);
        pk.us[4] = f2bf(b.x); pk.us[5] = f2bf(b.y); pk.us[6] = f2bf(b.z); pk.us[7] = f2bf(b.w);
        *(bf16x8*)(Xbf + unit * 8) = pk.v;
    }
    __syncthreads();
    {
        int b2 = lane >> 4, l = lane & 15;
        const float* s = &sq[w][b2 * 128];
        float t = __fadd_rn(
            __fadd_rn(__fadd_rn(s[l], s[16 + l]), __fadd_rn(s[32 + l], s[48 + l])),
            __fadd_rn(__fadd_rn(s[64 + l], s[80 + l]), __fadd_rn(s[96 + l], s[112 + l])));
        ub[w][lane] = t;
    }
    __syncthreads();
    if (lane < 4) {
        const float* u = &ub[w][lane * 16];
        float T3[8], T6[4];
        #pragma unroll
        for (int i = 0; i < 8; ++i) T3[i] = __fadd_rn(u[i], u[i + 8]);
        #pragma unroll
        for (int i = 0; i < 4; ++i) T6[i] = __fadd_rn(T3[i], T3[i + 4]);
        bb[w][lane] = __fadd_rn(__fadd_rn(T6[0], T6[2]), __fadd_rn(T6[1], T6[3]));
    }
    __syncthreads();
    if (lane == 0)
        *dst = __fadd_rn(__fadd_rn(bb[w][0], bb[w][1]), __fadd_rn(bb[w][2], bb[w][3]));
}

// E fp32 -> bf16 k-slice-major 32KB chunks (256 cols x 64 k). Fused hist/loss init.
// unit u within chunk: (ks*16+rf)*64+lane -> E[cb2*256+rf*16+(lane&15)][kt*64+ks*32+(lane>>4)*8..+7]
__global__ __launch_bounds__(256) void packE_kernel(const float* __restrict__ E,
                                                    unsigned short* __restrict__ Ebf2,
                                                    int* __restrict__ hist,
                                                    double* __restrict__ loss_acc) {
    int t = blockIdx.x * 256 + threadIdx.x;
    if (t < KK) hist[t] = 0;
    if (t == KK) *loss_acc = 0.0;
    int chunk = t >> 11, u = t & 2047;
    int ks = u >> 10, rf = (u >> 6) & 15, lane = u & 63;
    int col = (chunk >> 3) * 256 + rf * 16 + (lane & 15);
    int k   = (chunk & 7) * 64 + ks * 32 + (lane >> 4) * 8;
    const float4* s = (const float4*)(E + (size_t)col * DD + k);
    float4 a = s[0], b = s[1];
    union { bf16x8 v; unsigned short us[8]; } pk;
    pk.us[0] = f2bf(a.x); pk.us[1] = f2bf(a.y); pk.us[2] = f2bf(a.z); pk.us[3] = f2bf(a.w);
    pk.us[4] = f2bf(b.x); pk.us[5] = f2bf(b.y); pk.us[6] = f2bf(b.z); pk.us[7] = f2bf(b.w);
    *(bf16x8*)(Ebf2 + (size_t)t * 8) = pk.v;
}

// 8-phase counted-vmcnt GEMM screen. grid 2048 = 128 rb2 x 16 cb2 (XCD-swizzled),
// 512 thr (8 waves 2Mx4N). Dyn LDS 128KB: A [0,64K) = parity*32K + kh*16K;
// B [64K,128K) likewise. HT issue order per K-tile: A-k0,B-k0,A-k1,B-k1.
__global__ __launch_bounds__(512, 2) void gemm_screen(
    const unsigned short* __restrict__ Xbf, const unsigned short* __restrict__ Ebf2,
    const float* __restrict__ esqw, uint2* __restrict__ partials)
{
    extern __shared__ __align__(16) char pool[];

    const int tid = threadIdx.x;
    const int w = tid >> 6, lane = tid & 63;
    const int c = lane & 15, g = lane >> 4;
    const int bid = blockIdx.x;
    const int orig = (bid & 7) * 256 + (bid >> 3);   // bijective: 2048 % 8 == 0
    const int rb2 = orig >> 4, cb2 = orig & 15;
    const int row0 = rb2 * 256, col0 = cb2 * 256;
    const int mw = w >> 2, nw = w & 3;               // 2M x 4N

    const char* Xc = (const char*)Xbf  + (size_t)rb2 * 262144;
    const char* Ec = (const char*)Ebf2 + (size_t)cb2 * 262144;

    f32x4 acc[8][4];
    #pragma unroll
    for (int i = 0; i < 8; ++i)
        #pragma unroll
        for (int j = 0; j < 4; ++j) acc[i][j] = (f32x4){0.f, 0.f, 0.f, 0.f};

    // stage one 16KB half-tile (k-slice kh of K-tile tile_): 2 gll16/thread
    #define ISSUE(base_, tile_, kh_, bofs_) { \
        const char* s_ = (base_) + (size_t)(tile_) * 32768 + (kh_) * 16384 + (size_t)tid * 16; \
        char* d_ = pool + (bofs_) + (((tile_) & 1) * 32768) + (kh_) * 16384 + w * 1024; \
        gll16(s_, d_); gll16(s_ + 8192, d_ + 8192); }

    // phase p: quadrant (qk=(p>>1)&1, qm=p&1) of K-tile parity pt=p>>2
    #define PHASE(p_, STG_, WAIT_) { \
        const int pt_ = (p_) >> 2, qk_ = ((p_) >> 1) & 1, qm_ = (p_) & 1; \
        const char* Ap_ = pool + pt_ * 32768 + qk_ * 16384; \
        const char* Bp_ = pool + 65536 + pt_ * 32768 + qk_ * 16384; \
        bf16x8 af_[4], bf_[4]; \
        _Pragma("unroll") for (int ii = 0; ii < 4; ++ii) \
            af_[ii] = *(const bf16x8*)(Ap_ + (((mw * 8 + qm_ * 4 + ii) * 64) + lane) * 16); \
        _Pragma("unroll") for (int jj = 0; jj < 4; ++jj) \
            bf_[jj] = *(const bf16x8*)(Bp_ + (((nw * 4 + jj) * 64) + lane) * 16); \
        STG_; \
        WAIT_; \
        __builtin_amdgcn_s_barrier(); \
        __builtin_amdgcn_s_setprio(1); \
        _Pragma("unroll") for (int ii = 0; ii < 4; ++ii) \
            _Pragma("unroll") for (int jj = 0; jj < 4; ++jj) \
                acc[qm_ * 4 + ii][jj] = __builtin_amdgcn_mfma_f32_16x16x32_bf16( \
                    af_[ii], bf_[jj], acc[qm_ * 4 + ii][jj], 0, 0, 0); \
        __builtin_amdgcn_s_setprio(0); \
        __builtin_amdgcn_s_barrier(); }

    // prologue: K-tile 0 (4 HTs) + K-tile 1 A-k0,B-k0; wait all-but-2-HT; barrier
    ISSUE(Xc, 0, 0, 0); ISSUE(Ec, 0, 0, 65536);
    ISSUE(Xc, 0, 1, 0); ISSUE(Ec, 0, 1, 65536);
    ISSUE(Xc, 1, 0, 0); ISSUE(Ec, 1, 0, 65536);
    asm volatile("s_waitcnt vmcnt(4)" ::: "memory");
    __builtin_amdgcn_s_barrier();

    for (int i = 0; i < 4; ++i) {
        const int t1n = 2 * i + 1, t2n = 2 * i + 2, t3n = 2 * i + 3;
        PHASE(0, ISSUE(Xc, t1n, 1, 0), {});
        PHASE(1, ISSUE(Ec, t1n, 1, 65536), {});
        PHASE(2, if (i < 3) ISSUE(Xc, t2n, 0, 0), {});
        PHASE(3, if (i < 3) ISSUE(Ec, t2n, 0, 65536),
                 if (i < 3) { asm volatile("s_waitcnt vmcnt(4)" ::: "memory"); }
                 else       { asm volatile("s_waitcnt vmcnt(0)" ::: "memory"); });
        PHASE(4, if (i < 3) ISSUE(Xc, t2n, 1, 0), {});
        PHASE(5, if (i < 3) ISSUE(Ec, t2n, 1, 65536), {});
        PHASE(6, if (i < 3) ISSUE(Xc, t3n, 0, 0), {});
        PHASE(7, if (i < 3) ISSUE(Ec, t3n, 0, 65536),
                 if (i < 3) { asm volatile("s_waitcnt vmcnt(4)" ::: "memory"); });
    }

    // epilogue: per-(mf,r) top2 over 4 nf, shfl_xor merge across 16 c-lanes (R12-validated)
    float es[4];
    #pragma unroll
    for (int nf = 0; nf < 4; ++nf) es[nf] = esqw[col0 + nw * 64 + nf * 16 + c];
    #pragma unroll
    for (int mf = 0; mf < 8; ++mf) {
        #pragma unroll
        for (int r = 0; r < 4; ++r) {
            unsigned int q1 = 0xFFFFFFFFu, q2 = 0xFFFFFFFFu;
            #pragma unroll
            for (int nf = 0; nf < 4; ++nf) {
                int col = col0 + nw * 64 + nf * 16 + c;
                float s = fmaf(-2.0f, acc[mf][nf][r], es[nf]);
                unsigned int q = packscore(s, col);
                if (q < q1) { q2 = q1; q1 = q; } else if (q < q2) q2 = q;
            }
            #pragma unroll
            for (int off = 1; off < 16; off <<= 1) {
                unsigned int o1 = (unsigned int)__shfl_xor((int)q1, off, 64);
                unsigned int o2 = (unsigned int)__shfl_xor((int)q2, off, 64);
                unsigned int n1 = min(q1, o1);
                unsigned int n2 = min(max(q1, o1), min(q2, o2));
                q1 = n1; q2 = n2;
            }
            if (c == 0) {
                int row = row0 + mw * 128 + mf * 16 + g * 4 + r;
                partials[(size_t)(cb2 * 4 + nw) * BB + row] = make_uint2(q1, q2);
            }
        }
    }
    #undef ISSUE
    #undef PHASE
}

// merge partials -> candidates -> numpy-fp32 rescore -> idx/hist/loss (verbatim R11-R14)
__global__ __launch_bounds__(256) void reduce_kernel(
    const float* __restrict__ X, const float* __restrict__ E,
    const float* __restrict__ xsqw, const float* __restrict__ esqw,
    const uint2* __restrict__ partials, int* __restrict__ idxbuf,
    int* __restrict__ hist, double* __restrict__ loss_acc,
    float* __restrict__ out)
{
    __shared__ double lred[256];
    const int row = blockIdx.x * 256 + threadIdx.x;
    unsigned int m = 0xFFFFFFFFu;
    for (int e = 0; e < 64; ++e) m = min(m, partials[(size_t)e * BB + row].x);
    float lim = unpackscore(m) + MARG;
    int cand[NCAND]; int nc = 0;
    for (int e = 0; e < 64; ++e) {
        uint2 p = partials[(size_t)e * BB + row];
        if (unpackscore(p.x) <= lim && nc < NCAND) cand[nc++] = (int)(p.x & 0xFFFu);
        if (unpackscore(p.y) <= lim && nc < NCAND) cand[nc++] = (int)(p.y & 0xFFFu);
    }
    const float* xr = X + (size_t)row * DD;
    float xs = xsqw[row];
    float bd = 3.0e38f; int bk = 0x7fffffff;
    for (int cidx = 0; cidx < nc; ++cidx) {
        int k = cand[cidx] & (KK - 1);
        const float* er = E + (size_t)k * DD;
        float q1 = 0.f, q2 = 0.f;
        for (int d = 0; d < 384; ++d)   q1 = fmaf(xr[d], er[d], q1);
        for (int d = 384; d < 512; ++d) q2 = fmaf(xr[d], er[d], q2);
        float dot = __fadd_rn(q1, q2);
        float t1  = __fadd_rn(xs, esqw[k]);
        float dnp = __fsub_rn(t1, __fmul_rn(2.0f, dot));
        if (dnp < bd || (dnp == bd && k < bk)) { bd = dnp; bk = k; }
    }
    const float* er = E + (size_t)bk * DD;
    double ls = 0.0;
    for (int d = 0; d < DD; ++d) {
        double df = (double)xr[d] - (double)er[d];
        ls = fma(df, df, ls);
    }
    idxbuf[row] = bk;
    out[IDX_OFF + row] = (float)bk;
    atomicAdd(&hist[bk], 1);
    lred[threadIdx.x] = ls;
    __syncthreads();
    for (int t = 128; t > 0; t >>= 1) {
        if (threadIdx.x < t) lred[threadIdx.x] += lred[threadIdx.x + t];
        __syncthreads();
    }
    if (threadIdx.x == 0) atomicAdd(loss_acc, lred[0]);
}

// one block per row: quantized gather (coalesced) + one-hot row
__global__ __launch_bounds__(256) void encq_kernel(const int* __restrict__ idxbuf,
                                                   const float* __restrict__ E,
                                                   float* __restrict__ out) {
    int row = blockIdx.x;
    int idx = idxbuf[row];
    ((float2*)out)[(size_t)row * 256 + threadIdx.x] =
        ((const float2*)E)[(size_t)idx * 256 + threadIdx.x];
    float2* erow = (float2*)(out + ENC_OFF) + (size_t)row * (KK / 2);
    int half = idx >> 1;
    float2 one;
    if (idx & 1) { one.x = 0.f; one.y = 1.f; } else { one.x = 1.f; one.y = 0.f; }
    float2 z; z.x = 0.f; z.y = 0.f;
    for (int c = threadIdx.x; c < KK / 2; c += 256)
        erow[c] = (c == half) ? one : z;
}

__global__ __launch_bounds__(256) void fin_kernel(const int* __restrict__ hist,
                                                  const double* __restrict__ loss_acc,
                                                  float* __restrict__ out) {
    __shared__ double red[256];
    int tid = threadIdx.x;
    double s = 0.0;
    for (int k = tid; k < KK; k += 256) {
        double p = (double)hist[k] * (1.0 / 32768.0);
        s += p * log(p + 1e-10);
    }
    red[tid] = s;
    __syncthreads();
    for (int t = 128; t > 0; t >>= 1) {
        if (tid < t) red[tid] += red[tid + t];
        __syncthreads();
    }
    if (tid == 0) {
        double perp = exp(-red[0]);
        double L = loss_acc[0] * (1.0 / ((double)BB * (double)DD));
        out[LOSS_OFF] = (float)(1.25 * L);
        out[PERP_OFF] = (float)perp;
    }
}

extern "C" void kernel_launch(void* const* d_in, const int* in_sizes, int n_in,
                              void* d_out, int out_size, void* d_ws, size_t ws_size,
                              hipStream_t stream) {
    const float* X; const float* E;
    if (in_sizes[0] == BB * DD) { X = (const float*)d_in[0]; E = (const float*)d_in[1]; }
    else                        { X = (const float*)d_in[1]; E = (const float*)d_in[0]; }
    float* out = (float*)d_out;

    float* xsq = (float*)((char*)d_ws + WSB_XSQ);
    float* esq = (float*)((char*)d_ws + WSB_ESQ);
    int* idxbuf = (int*)((char*)d_ws + WSB_IDX);
    int* hist   = (int*)((char*)d_ws + WSB_HIST);
    double* loss_acc = (double*)((char*)d_ws + WSB_LOSS);
    unsigned short* Ebf2 = (unsigned short*)((char*)d_ws + WSB_EBF2);
    unsigned short* Xbf  = (unsigned short*)((char*)d_ws + WSB_XBF);
    uint2* partials = (uint2*)((char*)d_ws + WSB_PART);

    hipLaunchKernelGGL(npsum_pack_kernel, dim3((BB + KK) / 4), dim3(256), 0, stream,
                       X, E, xsq, esq, Xbf);
    hipLaunchKernelGGL(packE_kernel, dim3(1024), dim3(256), 0, stream,
                       E, Ebf2, hist, loss_acc);
    hipLaunchKernelGGL(gemm_screen, dim3(2048), dim3(512), 131072, stream,
                       Xbf, Ebf2, esq, partials);
    hipLaunchKernelGGL(reduce_kernel, dim3(BB / 256), dim3(256), 0, stream,
                       X, E, xsq, esq, partials, idxbuf, hist, loss_acc, out);
    hipLaunchKernelGGL(encq_kernel, dim3(BB), dim3(256), 0, stream, idxbuf, E, out);
    hipLaunchKernelGGL(fin_kernel, dim3(1), dim3(256), 0, stream, hist, loss_acc, out);
}